// Round 11
// baseline (6803.036 us; speedup 1.0000x reference)
//
#include <hip/hip_runtime.h>
#include <math.h>

typedef __attribute__((ext_vector_type(8))) short s16x8;
typedef __attribute__((ext_vector_type(8))) _Float16 f16x8;
typedef __attribute__((ext_vector_type(16))) float f32x16;
typedef unsigned long long u64;
typedef unsigned short u16;

#define NBLK 256
#define NTHR 512

constexpr int HSZ2 = 32 * 2048;  // one h slot, f16 elems

__device__ __forceinline__ float sigm(float v) { return 1.0f / (1.0f + expf(-v)); }

__device__ __forceinline__ unsigned short bf16_rne(float x) {
    unsigned u = __float_as_uint(x);
    return (unsigned short)((u + 0x7FFFu + ((u >> 16) & 1u)) >> 16);
}
__device__ __forceinline__ void split2(float x, unsigned short& hi, unsigned short& lo) {
    unsigned u = __float_as_uint(x);
    hi = (unsigned short)(u >> 16);
    float hf = __uint_as_float(u & 0xFFFF0000u);
    lo = bf16_rne(x - hf);
}
__device__ __forceinline__ void split8(const float* f, s16x8& h, s16x8& l) {
    #pragma unroll
    for (int i = 0; i < 8; ++i) {
        unsigned short hh, ll;
        split2(f[i], hh, ll);
        h[i] = (short)hh; l[i] = (short)ll;
    }
}

// ---- agent-scope stores (publish path; readers use plain cached loads on no-reuse slots) ----
__device__ __forceinline__ void ast64(u16* p, u64 v) {
    __hip_atomic_store((u64*)p, v, __ATOMIC_RELAXED, __HIP_MEMORY_SCOPE_AGENT);
}

// ---- all-poll barrier ----
__device__ __forceinline__ void pollall(const unsigned* arr, unsigned e) {
    if (threadIdx.x < 64) {
        const int i0 = (int)threadIdx.x * 4;
        for (;;) {
            bool ok = (__hip_atomic_load(arr + i0 + 0, __ATOMIC_RELAXED, __HIP_MEMORY_SCOPE_AGENT) >= e) &&
                      (__hip_atomic_load(arr + i0 + 1, __ATOMIC_RELAXED, __HIP_MEMORY_SCOPE_AGENT) >= e) &&
                      (__hip_atomic_load(arr + i0 + 2, __ATOMIC_RELAXED, __HIP_MEMORY_SCOPE_AGENT) >= e) &&
                      (__hip_atomic_load(arr + i0 + 3, __ATOMIC_RELAXED, __HIP_MEMORY_SCOPE_AGENT) >= e);
            if (__all(ok)) break;
            __builtin_amdgcn_s_sleep(1);
        }
    }
    __syncthreads();
}

// ---------- precompute: transpose [R][C] fp32 -> [C][R] bf16 hi/lo ----------
__global__ void transpose_split(const float* __restrict__ in,
                                u16* __restrict__ outHi, u16* __restrict__ outLo,
                                int R, int C) {
    __shared__ float tile[32][33];
    const int c0 = blockIdx.x * 32, r0 = blockIdx.y * 32;
    const int tid = threadIdx.x;  // 256
    {
        int r = tid >> 3, q = (tid & 7) * 4;
        float4 v = *(const float4*)(in + (size_t)(r0 + r) * C + c0 + q);
        tile[q + 0][r] = v.x; tile[q + 1][r] = v.y;
        tile[q + 2][r] = v.z; tile[q + 3][r] = v.w;
    }
    __syncthreads();
    {
        int c = tid >> 3, q = (tid & 7) * 4;
        ushort4 h, l;
        unsigned short hh, ll;
        split2(tile[c][q + 0], hh, ll); h.x = hh; l.x = ll;
        split2(tile[c][q + 1], hh, ll); h.y = hh; l.y = ll;
        split2(tile[c][q + 2], hh, ll); h.z = hh; l.z = ll;
        split2(tile[c][q + 3], hh, ll); h.w = hh; l.w = ll;
        size_t o = (size_t)(c0 + c) * R + r0 + q;
        *(ushort4*)(outHi + o) = h;
        *(ushort4*)(outLo + o) = l;
    }
}

// ---------- precompute: transpose [R][C] fp32 -> [C][R] f16 ----------
__global__ void transpose_f16(const float* __restrict__ in, u16* __restrict__ outp,
                              int R, int C) {
    __shared__ float tile[32][33];
    const int c0 = blockIdx.x * 32, r0 = blockIdx.y * 32;
    const int tid = threadIdx.x;  // 256
    {
        int r = tid >> 3, q = (tid & 7) * 4;
        float4 v = *(const float4*)(in + (size_t)(r0 + r) * C + c0 + q);
        tile[q + 0][r] = v.x; tile[q + 1][r] = v.y;
        tile[q + 2][r] = v.z; tile[q + 3][r] = v.w;
    }
    __syncthreads();
    {
        int c = tid >> 3, q = (tid & 7) * 4;
        ushort4 o;
        o.x = __builtin_bit_cast(u16, (_Float16)tile[c][q + 0]);
        o.y = __builtin_bit_cast(u16, (_Float16)tile[c][q + 1]);
        o.z = __builtin_bit_cast(u16, (_Float16)tile[c][q + 2]);
        o.w = __builtin_bit_cast(u16, (_Float16)tile[c][q + 3]);
        *(ushort4*)(outp + (size_t)(c0 + c) * R + r0 + q) = o;
    }
}

// ---------- precompute: Qt[8192][2048] f16 = (P[2048][640] @ Wpart[640][8192])^T ----------
// rowOff selects the W k-rows: 0 = x/m0-input part, 640 = recurrent part.
__global__ void __launch_bounds__(256) qgemm(const float* __restrict__ P,
    const u16* __restrict__ WH, const u16* __restrict__ WL,
    u16* __restrict__ Qt, int rowOff) {
    const int tid = threadIdx.x;
    const int wid = tid >> 6, lane = tid & 63;
    const int n = lane & 31, kg = lane >> 5;
    const int tile = blockIdx.x * 4 + wid;
    const int ct = tile & 255, kt = tile >> 8;
    const int col = ct * 32 + n;
    const int krow = kt * 32 + n;

    f32x16 acc;
    #pragma unroll
    for (int r = 0; r < 16; ++r) acc[r] = 0.f;

    const float* ap = P + (size_t)krow * 640 + kg * 8;
    const u16* bhp = WH + (size_t)col * 1280 + rowOff + kg * 8;
    const u16* blp = WL + (size_t)col * 1280 + rowOff + kg * 8;
    #pragma unroll 4
    for (int ks = 0; ks < 40; ++ks) {
        float4 v0 = *(const float4*)(ap + ks * 16);
        float4 v1 = *(const float4*)(ap + ks * 16 + 4);
        float f[8] = {v0.x, v0.y, v0.z, v0.w, v1.x, v1.y, v1.z, v1.w};
        s16x8 ah, al;
        split8(f, ah, al);
        s16x8 bh = *(const s16x8*)(bhp + ks * 16);
        s16x8 bl = *(const s16x8*)(blp + ks * 16);
        acc = __builtin_amdgcn_mfma_f32_32x32x16_bf16(ah, bh, acc, 0, 0, 0);
        acc = __builtin_amdgcn_mfma_f32_32x32x16_bf16(ah, bl, acc, 0, 0, 0);
        acc = __builtin_amdgcn_mfma_f32_32x32x16_bf16(al, bh, acc, 0, 0, 0);
    }
    u16* qrow = Qt + (size_t)col * 2048 + kt * 32 + 4 * kg;
    #pragma unroll
    for (int q = 0; q < 4; ++q) {
        ushort4 o;
        o.x = __builtin_bit_cast(u16, (_Float16)acc[4 * q + 0]);
        o.y = __builtin_bit_cast(u16, (_Float16)acc[4 * q + 1]);
        o.z = __builtin_bit_cast(u16, (_Float16)acc[4 * q + 2]);
        o.w = __builtin_bit_cast(u16, (_Float16)acc[4 * q + 3]);
        *(ushort4*)(qrow + 8 * q) = o;
    }
}

// ---------- main persistent kernel ----------
// z0(t) = x(t)Wx0 + h0(t-1)Q0          (Q0  = P0@Wm0)
// z1(s) = h0(s)Q01 + h1(s-1)Q1, s=g-1  (Q01 = P0@Wx1, Q1 = P1@Wm1)
// out(t) = h1(t)@P1 (teams, post-arrive). No m0 ring. 257 intervals, one flag each.
// All 3 Q slices pinned in the unified VGPR/AGPR file (192 regs).
__global__ void __launch_bounds__(NTHR, 2) lstm_pipe(
    const float* __restrict__ x,
    const float* __restrict__ bias0, const float* __restrict__ bias1,
    const u16* __restrict__ Wxt0,
    const u16* __restrict__ Qt0, const u16* __restrict__ Qt01, const u16* __restrict__ Qt1,
    const u16* __restrict__ Pt1,
    u16* __restrict__ hb0, u16* __restrict__ hb1,   // [256][32][2048] f16 each (no-reuse)
    float* out, unsigned* arr) {
    __shared__ float part[8][64][20];
    __shared__ float zb0[32][33];
    __shared__ float zb1[32][33];
    __shared__ u16 hst0[32][8];
    __shared__ u16 hst1[32][8];

    const int tid = threadIdx.x, bid = blockIdx.x;
    const int wid = tid >> 6, lane = tid & 63;
    const int n = lane & 31, kg = lane >> 5;

    const int colmap = (n >> 3) * 2048 + bid * 8 + (n & 7);
    const size_t wx640 = (size_t)colmap * 640 + wid * 80 + kg * 8;    // Wxt0 slice
    const size_t qOff  = (size_t)colmap * 2048 + wid * 256 + kg * 8;  // Qt slices
    const size_t aXf   = (size_t)n * (256 * 640) + wid * 80 + kg * 8; // x row n (f32), +t*640
    const size_t hROff = (size_t)n * 2048 + wid * 256 + kg * 8;       // h frag base

    // D layout: col=lane&31, row=(reg&3)+8*(reg>>2)+4*(lane>>5)
    const int rn = tid >> 4, rm0 = (tid & 15) * 2;
    const int ch = tid >> 5, cb = tid & 31;   // cell mapping (tid<256)

    const bool isT = bid < 40;
    const int  tb  = (bid < 20) ? bid : bid - 20;
    const int  par = (bid < 20) ? 0 : 1;
    const size_t pOff = (size_t)(tb * 32 + n) * 2048 + wid * 256 + kg * 8;

    const float bv0 = bias0[(rn >> 3) * 2048 + bid * 8 + (rn & 7)];
    const float bv1 = bias1[(rn >> 3) * 2048 + bid * 8 + (rn & 7)];

    // ---- load + PIN all three Q fragment sets (192 regs in unified file) ----
    uint4 q0r[16], q01r[16], q1r[16];
    #pragma unroll
    for (int ks = 0; ks < 16; ++ks) {
        q0r[ks]  = *(const uint4*)(Qt0  + qOff + ks * 16);
        q01r[ks] = *(const uint4*)(Qt01 + qOff + ks * 16);
        q1r[ks]  = *(const uint4*)(Qt1  + qOff + ks * 16);
    }
    #pragma unroll
    for (int ks = 0; ks < 16; ++ks) {
        asm volatile("" : "+v"(q0r[ks].x),  "+v"(q0r[ks].y),  "+v"(q0r[ks].z),  "+v"(q0r[ks].w));
        asm volatile("" : "+v"(q01r[ks].x), "+v"(q01r[ks].y), "+v"(q01r[ks].z), "+v"(q01r[ks].w));
        asm volatile("" : "+v"(q1r[ks].x),  "+v"(q1r[ks].y),  "+v"(q1r[ks].z),  "+v"(q1r[ks].w));
    }

    float creg0 = 0.f, creg1 = 0.f;

    auto xp0 = [&](int t) -> f32x16 {   // x(t) @ Wxt0; f32 x cast to f16 in-loop (post-arrive)
        f32x16 a;
        #pragma unroll
        for (int r = 0; r < 16; ++r) a[r] = 0.f;
        const float* xb = x + aXf + (size_t)t * 640;
        const u16* wb = Wxt0 + wx640;
        #pragma unroll
        for (int ks = 0; ks < 5; ++ks) {
            float4 v0 = *(const float4*)(xb + ks * 16);
            float4 v1 = *(const float4*)(xb + ks * 16 + 4);
            f16x8 av;
            av[0] = (_Float16)v0.x; av[1] = (_Float16)v0.y;
            av[2] = (_Float16)v0.z; av[3] = (_Float16)v0.w;
            av[4] = (_Float16)v1.x; av[5] = (_Float16)v1.y;
            av[6] = (_Float16)v1.z; av[7] = (_Float16)v1.w;
            a = __builtin_amdgcn_mfma_f32_32x32x16_f16(av, *(const f16x8*)(wb + ks * 16), a, 0, 0, 0);
        }
        return a;
    };
    auto stash = [&](const f32x16& v) {
        #pragma unroll
        for (int r = 0; r < 4; ++r) {
            float4 w;
            w.x = v[4 * r + 0]; w.y = v[4 * r + 1];
            w.z = v[4 * r + 2]; w.w = v[4 * r + 3];
            *(float4*)&part[wid][lane][4 * r] = w;
        }
    };
    auto sum8 = [&](int m) -> float {
        int lp = rn + 32 * ((m >> 2) & 1);
        int rg = (m & 3) + 4 * (m >> 3);
        float s = 0.f;
        #pragma unroll
        for (int w = 0; w < 8; ++w) s += part[w][lp][rg];
        return s;
    };

    f32x16 zacc0 = xp0(0);

    for (int g = 0; g <= 257; ++g) {
        if (g > 0) pollall(arr, (unsigned)g);   // h0(g-1), h1(g-2) + flags visible
        const int s = g - 1;                    // L1 step this interval
        const bool doL0 = (g <= 255);
        const bool doL1 = (s >= 0 && s <= 255);

        // ===== both gate chains: same h0(g-1) operand, independent accumulators =====
        f32x16 acc0, acc1;
        if (doL0) acc0 = zacc0;
        if (doL1) {
            #pragma unroll
            for (int r = 0; r < 16; ++r) acc1[r] = 0.f;
        }
        if (g >= 1) {
            const u16* h0c = hb0 + (size_t)(g - 1) * HSZ2 + hROff;
            if (doL0 && doL1) {
                #pragma unroll
                for (int ks = 0; ks < 16; ++ks) {
                    f16x8 a = *(const f16x8*)(h0c + ks * 16);
                    acc0 = __builtin_amdgcn_mfma_f32_32x32x16_f16(a, __builtin_bit_cast(f16x8, q0r[ks]),  acc0, 0, 0, 0);
                    acc1 = __builtin_amdgcn_mfma_f32_32x32x16_f16(a, __builtin_bit_cast(f16x8, q01r[ks]), acc1, 0, 0, 0);
                }
            } else if (doL0) {
                #pragma unroll
                for (int ks = 0; ks < 16; ++ks)
                    acc0 = __builtin_amdgcn_mfma_f32_32x32x16_f16(*(const f16x8*)(h0c + ks * 16),
                                                                  __builtin_bit_cast(f16x8, q0r[ks]), acc0, 0, 0, 0);
            } else if (doL1) {
                #pragma unroll
                for (int ks = 0; ks < 16; ++ks)
                    acc1 = __builtin_amdgcn_mfma_f32_32x32x16_f16(*(const f16x8*)(h0c + ks * 16),
                                                                  __builtin_bit_cast(f16x8, q01r[ks]), acc1, 0, 0, 0);
            }
        }
        if (s >= 1) {   // + h1(s-1) · Q1
            const u16* h1c = hb1 + (size_t)(s - 1) * HSZ2 + hROff;
            #pragma unroll
            for (int ks = 0; ks < 16; ++ks)
                acc1 = __builtin_amdgcn_mfma_f32_32x32x16_f16(*(const f16x8*)(h1c + ks * 16),
                                                              __builtin_bit_cast(f16x8, q1r[ks]), acc1, 0, 0, 0);
        }

        // ===== reduces (part shared, 2 passes) + cells =====
        if (doL0) {
            stash(acc0);
            __syncthreads();
            #pragma unroll
            for (int j = 0; j < 2; ++j) { int m = rm0 + j; zb0[rn][m] = sum8(m) + bv0; }
        }
        __syncthreads();
        if (doL1) {
            stash(acc1);
            __syncthreads();
            #pragma unroll
            for (int j = 0; j < 2; ++j) { int m = rm0 + j; zb1[rn][m] = sum8(m) + bv1; }
        }
        if (doL0 && tid < 256) {   // cell0 (gate order i, j, f, o) — zb0 stable 2 syncs ago
            float zi = zb0[0 * 8 + ch][cb];
            float zj = zb0[1 * 8 + ch][cb];
            float zf = zb0[2 * 8 + ch][cb];
            float zo = zb0[3 * 8 + ch][cb];
            float cn = sigm(zf + 1.0f) * creg0 + sigm(zi) * tanhf(zj);
            creg0 = cn;
            hst0[cb][ch] = __builtin_bit_cast(u16, (_Float16)(sigm(zo) * tanhf(cn)));
        }
        __syncthreads();
        if (doL1 && tid < 256) {   // cell1
            float zi = zb1[0 * 8 + ch][cb];
            float zj = zb1[1 * 8 + ch][cb];
            float zf = zb1[2 * 8 + ch][cb];
            float zo = zb1[3 * 8 + ch][cb];
            float cn = sigm(zf + 1.0f) * creg1 + sigm(zi) * tanhf(zj);
            creg1 = cn;
            hst1[cb][ch] = __builtin_bit_cast(u16, (_Float16)(sigm(zo) * tanhf(cn)));
        }
        __syncthreads();

        // ===== publish + arrive =====
        if (doL0 && wid == 0) {
            int b = tid >> 1, hf = tid & 1;
            u64 v = *(const u64*)&hst0[b][hf * 4];
            ast64(hb0 + (size_t)g * HSZ2 + (size_t)b * 2048 + bid * 8 + hf * 4, v);
        }
        if (doL1 && wid == 1) {
            int l = tid - 64;
            int b = l >> 1, hf = l & 1;
            u64 v = *(const u64*)&hst1[b][hf * 4];
            ast64(hb1 + (size_t)s * HSZ2 + (size_t)b * 2048 + bid * 8 + hf * 4, v);
        }
        __syncthreads();   // drains publish stores (vmcnt before s_barrier)
        if (tid == 0)
            __hip_atomic_store(arr + bid, (unsigned)(g + 1), __ATOMIC_RELAXED, __HIP_MEMORY_SCOPE_AGENT);

        // ===== post-arrive (off critical path) =====
        const int sp = g - 2;   // output step for teams; h1(sp) visible since poll(g)
        if (isT && sp >= 0 && (sp & 1) == par) {
            f32x16 pacc;
            #pragma unroll
            for (int r = 0; r < 16; ++r) pacc[r] = 0.f;
            const u16* hc = hb1 + (size_t)sp * HSZ2 + hROff;
            const u16* pf = Pt1 + pOff;
            #pragma unroll
            for (int ks = 0; ks < 16; ++ks)
                pacc = __builtin_amdgcn_mfma_f32_32x32x16_f16(*(const f16x8*)(hc + ks * 16),
                                                              *(const f16x8*)(pf + ks * 16), pacc, 0, 0, 0);
            __syncthreads();
            stash(pacc);
            __syncthreads();
            #pragma unroll
            for (int j = 0; j < 2; ++j) {
                int m = rm0 + j;
                out[((size_t)m * 256 + sp) * 640 + tb * 32 + rn] = sum8(m);
            }
        }
        if (g < 255) zacc0 = xp0(g + 1);
    }
}

// ---------- fallback (R1-style) if ws too small ----------
__device__ __forceinline__ void grid_bar_slow(unsigned int* bar, unsigned int& epoch) {
    __syncthreads();
    epoch++;
    if (threadIdx.x == 0) {
        __threadfence();
        atomicAdd(bar, 1u);
        const unsigned int target = epoch * NBLK;
        while (__hip_atomic_load(bar, __ATOMIC_RELAXED, __HIP_MEMORY_SCOPE_AGENT) < target)
            __builtin_amdgcn_s_sleep(1);
        __threadfence();
    }
    __syncthreads();
}

__global__ void __launch_bounds__(NTHR, 1) lstm_fb(
    const float* __restrict__ x,
    const float* __restrict__ W0, const float* __restrict__ b0, const float* __restrict__ Pr0,
    const float* __restrict__ W1, const float* __restrict__ b1, const float* __restrict__ Pr1,
    float* out, float* ws) {
    const int tid = threadIdx.x;
    const int bid = blockIdx.x;
    unsigned int* bar = (unsigned int*)ws;
    float* mbuf0 = ws + 1024;
    float* mbuf1 = mbuf0 + 32 * 640;
    float* hws = mbuf1 + 32 * 640;
    __shared__ float zbuf[32 * 33];
    __shared__ float pred[512];
    unsigned int epoch = 0;
    const int c_idx = tid & 31;
    const int bg = tid >> 5;
    const int b0r = bg * 2;
    const int col = (c_idx >> 3) * 2048 + bid * 8 + (c_idx & 7);
    const int ch = tid >> 5;
    const int cb = tid & 31;
    const int p_s = (bid * 640) / NBLK;
    const int p_e = ((bid + 1) * 640) / NBLK;
    const int np = p_e - p_s;
    const int kq_n = (np == 2) ? 8 : 4;
    const int klen = 2048 / kq_n;
    const int pg = tid >> 5;
    const bool pact = pg < np * kq_n;
    const int pj = pact ? (pg % np) : 0;
    const int kq = pact ? (pg / np) : 0;
    for (int layer = 0; layer < 2; ++layer) {
        const float* W = layer ? W1 : W0;
        const float* bbv = layer ? b1 : b0;
        const float* Pr = layer ? Pr1 : Pr0;
        const float* inb = layer ? (const float*)out : x;
        for (int i = bid * NTHR + tid; i < 32 * 640; i += NBLK * NTHR) mbuf0[i] = 0.0f;
        float creg = 0.0f;
        grid_bar_slow(bar, epoch);
        const float bias = bbv[col];
        for (int t = 0; t < 256; ++t) {
            float* mcur = (t & 1) ? mbuf1 : mbuf0;
            float* mnxt = (t & 1) ? mbuf0 : mbuf1;
            const float* in0 = inb + (size_t)(b0r * 256 + t) * 640;
            const float* in1 = in0 + (size_t)256 * 640;
            const float* wp = W + col;
            float a0 = 0.f, a1 = 0.f;
            #pragma unroll 4
            for (int k = 0; k < 640; k += 4) {
                float4 u0 = *(const float4*)(in0 + k);
                float4 u1 = *(const float4*)(in1 + k);
                float w0 = wp[(size_t)(k + 0) * 8192], w1 = wp[(size_t)(k + 1) * 8192];
                float w2 = wp[(size_t)(k + 2) * 8192], w3 = wp[(size_t)(k + 3) * 8192];
                a0 += w0 * u0.x + w1 * u0.y + w2 * u0.z + w3 * u0.w;
                a1 += w0 * u1.x + w1 * u1.y + w2 * u1.z + w3 * u1.w;
            }
            const float* q0 = mcur + (size_t)b0r * 640;
            const float* q1 = q0 + 640;
            #pragma unroll 4
            for (int k = 0; k < 640; k += 4) {
                float4 u0 = *(const float4*)(q0 + k);
                float4 u1 = *(const float4*)(q1 + k);
                float w0 = wp[(size_t)(640 + k + 0) * 8192], w1 = wp[(size_t)(640 + k + 1) * 8192];
                float w2 = wp[(size_t)(640 + k + 2) * 8192], w3 = wp[(size_t)(640 + k + 3) * 8192];
                a0 += w0 * u0.x + w1 * u0.y + w2 * u0.z + w3 * u0.w;
                a1 += w0 * u1.x + w1 * u1.y + w2 * u1.z + w3 * u1.w;
            }
            zbuf[c_idx * 33 + b0r + 0] = a0 + bias;
            zbuf[c_idx * 33 + b0r + 1] = a1 + bias;
            __syncthreads();
            if (tid < 256) {
                float zi = zbuf[(0 * 8 + ch) * 33 + cb];
                float zj = zbuf[(1 * 8 + ch) * 33 + cb];
                float zf = zbuf[(2 * 8 + ch) * 33 + cb];
                float zo = zbuf[(3 * 8 + ch) * 33 + cb];
                float cn = sigm(zf + 1.0f) * creg + sigm(zi) * tanhf(zj);
                creg = cn;
                hws[(size_t)(bid * 8 + ch) * 32 + cb] = sigm(zo) * tanhf(cn);
            }
            grid_bar_slow(bar, epoch);
            if (pact) {
                const int p = p_s + pj;
                const float* pp = Pr + p;
                const int k0 = kq * klen;
                float s = 0.f;
                #pragma unroll 4
                for (int k = k0; k < k0 + klen; ++k) s += hws[(size_t)k * 32 + cb] * pp[(size_t)k * 640];
                pred[(pj * 32 + cb) * kq_n + kq] = s;
            }
            __syncthreads();
            if (tid < np * 32) {
                float s = 0.f;
                for (int q2 = 0; q2 < kq_n; ++q2) s += pred[tid * kq_n + q2];
                const int p = p_s + (tid >> 5);
                const int b = tid & 31;
                mnxt[(size_t)b * 640 + p] = s;
                out[((size_t)b * 256 + t) * 640 + p] = s;
            }
            grid_bar_slow(bar, epoch);
        }
    }
}

extern "C" void kernel_launch(void* const* d_in, const int* in_sizes, int n_in,
                              void* d_out, int out_size, void* d_ws, size_t ws_size,
                              hipStream_t stream) {
    const float* x   = (const float*)d_in[0];
    const float* W0  = (const float*)d_in[1];
    const float* b0  = (const float*)d_in[2];
    const float* P0  = (const float*)d_in[3];
    const float* W1  = (const float*)d_in[4];
    const float* b1  = (const float*)d_in[5];
    const float* P1  = (const float*)d_in[6];
    float* out = (float*)d_out;

    // ws layout (bytes, 256-aligned). One transpose-plane pair reused serially.
    size_t off = 0;
    auto alloc = [&](size_t bytes) { size_t o = off; off += (bytes + 255) & ~(size_t)255; return o; };
    const size_t oBar  = alloc(32768);
    const size_t szW   = (size_t)8192 * 1280 * 2;  // bf16 plane (scratch, reused)
    const size_t szQ   = (size_t)8192 * 2048 * 2;  // Qt f16
    const size_t szPt  = (size_t)640 * 2048 * 2;   // Pt f16
    const size_t szWx  = (size_t)8192 * 640 * 2;   // Wxt f16
    const size_t oWH   = alloc(szW), oWL = alloc(szW);
    const size_t oQt0  = alloc(szQ), oQt01 = alloc(szQ), oQt1 = alloc(szQ);
    const size_t oPt1  = alloc(szPt);
    const size_t oWx0  = alloc(szWx);
    const size_t oH0   = alloc((size_t)256 * HSZ2 * 2);   // no-reuse h rings
    const size_t oH1   = alloc((size_t)256 * HSZ2 * 2);
    const size_t need  = off;

    hipMemsetAsync(d_ws, 0, 32768, stream);  // barrier flags start at 0 every call

    if (ws_size < need) {  // fallback path (~0.5 MB ws)
        float* ws = (float*)d_ws;
        void* args[] = {(void*)&x, (void*)&W0, (void*)&b0, (void*)&P0,
                        (void*)&W1, (void*)&b1, (void*)&P1, (void*)&out, (void*)&ws};
        hipError_t err = hipLaunchCooperativeKernel((const void*)lstm_fb,
                                                    dim3(NBLK), dim3(NTHR), args, 0, stream);
        if (err != hipSuccess)
            lstm_fb<<<dim3(NBLK), dim3(NTHR), 0, stream>>>(x, W0, b0, P0, W1, b1, P1, out, ws);
        return;
    }

    char* w = (char*)d_ws;
    u16 *WHp = (u16*)(w + oWH), *WLp = (u16*)(w + oWL);
    u16 *Qt0p = (u16*)(w + oQt0), *Qt01p = (u16*)(w + oQt01), *Qt1p = (u16*)(w + oQt1);
    u16 *Pt1p = (u16*)(w + oPt1);
    u16 *Wx0p = (u16*)(w + oWx0);
    u16 *hb0p = (u16*)(w + oH0), *hb1p = (u16*)(w + oH1);
    unsigned* arrp = (unsigned*)(w + oBar);

    // precompute (stream-ordered; plane pair reused between layers)
    transpose_split<<<dim3(256, 40), 256, 0, stream>>>(W0, WHp, WLp, 1280, 8192);
    qgemm<<<dim3(4096), 256, 0, stream>>>(P0, WHp, WLp, Qt0p, 640);   // Q0  = P0 @ Wm0
    transpose_split<<<dim3(256, 40), 256, 0, stream>>>(W1, WHp, WLp, 1280, 8192);
    qgemm<<<dim3(4096), 256, 0, stream>>>(P0, WHp, WLp, Qt01p, 0);    // Q01 = P0 @ Wx1
    qgemm<<<dim3(4096), 256, 0, stream>>>(P1, WHp, WLp, Qt1p, 640);   // Q1  = P1 @ Wm1
    transpose_f16<<<dim3(20, 64), 256, 0, stream>>>(P1, Pt1p, 2048, 640);
    transpose_f16<<<dim3(256, 20), 256, 0, stream>>>(W0, Wx0p, 640, 8192);

    const float *b0c = b0, *b1c = b1;
    void* args[] = {(void*)&x, (void*)&b0c, (void*)&b1c,
                    (void*)&Wx0p,
                    (void*)&Qt0p, (void*)&Qt01p, (void*)&Qt1p, (void*)&Pt1p,
                    (void*)&hb0p, (void*)&hb1p,
                    (void*)&out, (void*)&arrp};
    hipError_t err = hipLaunchCooperativeKernel((const void*)lstm_pipe,
                                                dim3(NBLK), dim3(NTHR), args, 0, stream);
    if (err != hipSuccess)
        lstm_pipe<<<dim3(NBLK), dim3(NTHR), 0, stream>>>(
            x, b0c, b1c, Wx0p, Qt0p, Qt01p, Qt1p, Pt1p, hb0p, hb1p, out, arrp);
}

// Round 12
// 6280.582 us; speedup vs baseline: 1.0832x; 1.0832x over previous
//
#include <hip/hip_runtime.h>
#include <math.h>

typedef __attribute__((ext_vector_type(8))) short s16x8;
typedef __attribute__((ext_vector_type(8))) _Float16 f16x8;
typedef __attribute__((ext_vector_type(16))) float f32x16;
typedef unsigned long long u64;
typedef unsigned short u16;

#define NBLK 256
#define NTHR 512

constexpr int HSZ2 = 32 * 2048;  // one h slot, f16 elems

__device__ __forceinline__ float sigm(float v) { return 1.0f / (1.0f + expf(-v)); }

__device__ __forceinline__ unsigned short bf16_rne(float x) {
    unsigned u = __float_as_uint(x);
    return (unsigned short)((u + 0x7FFFu + ((u >> 16) & 1u)) >> 16);
}
__device__ __forceinline__ void split2(float x, unsigned short& hi, unsigned short& lo) {
    unsigned u = __float_as_uint(x);
    hi = (unsigned short)(u >> 16);
    float hf = __uint_as_float(u & 0xFFFF0000u);
    lo = bf16_rne(x - hf);
}
__device__ __forceinline__ void split8(const float* f, s16x8& h, s16x8& l) {
    #pragma unroll
    for (int i = 0; i < 8; ++i) {
        unsigned short hh, ll;
        split2(f[i], hh, ll);
        h[i] = (short)hh; l[i] = (short)ll;
    }
}

// ---- agent-scope stores (publish path; readers use plain cached loads on no-reuse slots) ----
__device__ __forceinline__ void ast64(u16* p, u64 v) {
    __hip_atomic_store((u64*)p, v, __ATOMIC_RELAXED, __HIP_MEMORY_SCOPE_AGENT);
}

// ---- all-poll barrier ----
__device__ __forceinline__ void pollall(const unsigned* arr, unsigned e) {
    if (threadIdx.x < 64) {
        const int i0 = (int)threadIdx.x * 4;
        for (;;) {
            bool ok = (__hip_atomic_load(arr + i0 + 0, __ATOMIC_RELAXED, __HIP_MEMORY_SCOPE_AGENT) >= e) &&
                      (__hip_atomic_load(arr + i0 + 1, __ATOMIC_RELAXED, __HIP_MEMORY_SCOPE_AGENT) >= e) &&
                      (__hip_atomic_load(arr + i0 + 2, __ATOMIC_RELAXED, __HIP_MEMORY_SCOPE_AGENT) >= e) &&
                      (__hip_atomic_load(arr + i0 + 3, __ATOMIC_RELAXED, __HIP_MEMORY_SCOPE_AGENT) >= e);
            if (__all(ok)) break;
            __builtin_amdgcn_s_sleep(1);
        }
    }
    __syncthreads();
}

// ---------- precompute: transpose [R][C] fp32 -> [C][R] bf16 hi/lo ----------
__global__ void transpose_split(const float* __restrict__ in,
                                u16* __restrict__ outHi, u16* __restrict__ outLo,
                                int R, int C) {
    __shared__ float tile[32][33];
    const int c0 = blockIdx.x * 32, r0 = blockIdx.y * 32;
    const int tid = threadIdx.x;  // 256
    {
        int r = tid >> 3, q = (tid & 7) * 4;
        float4 v = *(const float4*)(in + (size_t)(r0 + r) * C + c0 + q);
        tile[q + 0][r] = v.x; tile[q + 1][r] = v.y;
        tile[q + 2][r] = v.z; tile[q + 3][r] = v.w;
    }
    __syncthreads();
    {
        int c = tid >> 3, q = (tid & 7) * 4;
        ushort4 h, l;
        unsigned short hh, ll;
        split2(tile[c][q + 0], hh, ll); h.x = hh; l.x = ll;
        split2(tile[c][q + 1], hh, ll); h.y = hh; l.y = ll;
        split2(tile[c][q + 2], hh, ll); h.z = hh; l.z = ll;
        split2(tile[c][q + 3], hh, ll); h.w = hh; l.w = ll;
        size_t o = (size_t)(c0 + c) * R + r0 + q;
        *(ushort4*)(outHi + o) = h;
        *(ushort4*)(outLo + o) = l;
    }
}

// ---------- precompute: transpose [R][C] fp32 -> [C][R] f16 ----------
__global__ void transpose_f16(const float* __restrict__ in, u16* __restrict__ outp,
                              int R, int C) {
    __shared__ float tile[32][33];
    const int c0 = blockIdx.x * 32, r0 = blockIdx.y * 32;
    const int tid = threadIdx.x;  // 256
    {
        int r = tid >> 3, q = (tid & 7) * 4;
        float4 v = *(const float4*)(in + (size_t)(r0 + r) * C + c0 + q);
        tile[q + 0][r] = v.x; tile[q + 1][r] = v.y;
        tile[q + 2][r] = v.z; tile[q + 3][r] = v.w;
    }
    __syncthreads();
    {
        int c = tid >> 3, q = (tid & 7) * 4;
        ushort4 o;
        o.x = __builtin_bit_cast(u16, (_Float16)tile[c][q + 0]);
        o.y = __builtin_bit_cast(u16, (_Float16)tile[c][q + 1]);
        o.z = __builtin_bit_cast(u16, (_Float16)tile[c][q + 2]);
        o.w = __builtin_bit_cast(u16, (_Float16)tile[c][q + 3]);
        *(ushort4*)(outp + (size_t)(c0 + c) * R + r0 + q) = o;
    }
}

// ---------- precompute: x f32 -> f16 (same layout) ----------
__global__ void xcast(const float* __restrict__ in, u16* __restrict__ outp, int n4) {
    int i = blockIdx.x * blockDim.x + threadIdx.x;
    if (i < n4) {
        float4 v = ((const float4*)in)[i];
        ushort4 o;
        o.x = __builtin_bit_cast(u16, (_Float16)v.x);
        o.y = __builtin_bit_cast(u16, (_Float16)v.y);
        o.z = __builtin_bit_cast(u16, (_Float16)v.z);
        o.w = __builtin_bit_cast(u16, (_Float16)v.w);
        ((ushort4*)outp)[i] = o;
    }
}

// ---------- precompute: Qt[8192][2048] f16 = (P[2048][640] @ Wpart[640][8192])^T ----------
// rowOff selects the W k-rows: 0 = x/m0-input part, 640 = recurrent part.
__global__ void __launch_bounds__(256) qgemm(const float* __restrict__ P,
    const u16* __restrict__ WH, const u16* __restrict__ WL,
    u16* __restrict__ Qt, int rowOff) {
    const int tid = threadIdx.x;
    const int wid = tid >> 6, lane = tid & 63;
    const int n = lane & 31, kg = lane >> 5;
    const int tile = blockIdx.x * 4 + wid;
    const int ct = tile & 255, kt = tile >> 8;
    const int col = ct * 32 + n;
    const int krow = kt * 32 + n;

    f32x16 acc;
    #pragma unroll
    for (int r = 0; r < 16; ++r) acc[r] = 0.f;

    const float* ap = P + (size_t)krow * 640 + kg * 8;
    const u16* bhp = WH + (size_t)col * 1280 + rowOff + kg * 8;
    const u16* blp = WL + (size_t)col * 1280 + rowOff + kg * 8;
    #pragma unroll 4
    for (int ks = 0; ks < 40; ++ks) {
        float4 v0 = *(const float4*)(ap + ks * 16);
        float4 v1 = *(const float4*)(ap + ks * 16 + 4);
        float f[8] = {v0.x, v0.y, v0.z, v0.w, v1.x, v1.y, v1.z, v1.w};
        s16x8 ah, al;
        split8(f, ah, al);
        s16x8 bh = *(const s16x8*)(bhp + ks * 16);
        s16x8 bl = *(const s16x8*)(blp + ks * 16);
        acc = __builtin_amdgcn_mfma_f32_32x32x16_bf16(ah, bh, acc, 0, 0, 0);
        acc = __builtin_amdgcn_mfma_f32_32x32x16_bf16(ah, bl, acc, 0, 0, 0);
        acc = __builtin_amdgcn_mfma_f32_32x32x16_bf16(al, bh, acc, 0, 0, 0);
    }
    u16* qrow = Qt + (size_t)col * 2048 + kt * 32 + 4 * kg;
    #pragma unroll
    for (int q = 0; q < 4; ++q) {
        ushort4 o;
        o.x = __builtin_bit_cast(u16, (_Float16)acc[4 * q + 0]);
        o.y = __builtin_bit_cast(u16, (_Float16)acc[4 * q + 1]);
        o.z = __builtin_bit_cast(u16, (_Float16)acc[4 * q + 2]);
        o.w = __builtin_bit_cast(u16, (_Float16)acc[4 * q + 3]);
        *(ushort4*)(qrow + 8 * q) = o;
    }
}

// ---------- main persistent kernel ----------
// z0(t) = x(t)Wx0 + h0(t-1)Q0          (Q0  = P0@Wm0)
// z1(s) = h0(s)Q01 + h1(s-1)Q1, s=g-1  (Q01 = P0@Wx1, Q1 = P1@Wm1)
// out(t) = h1(t)@P1 (teams, post-arrive). 257 intervals, one flag each.
// __launch_bounds__(512, 1): 512-reg/wave cap. R11 lesson: the (512,2) 256-reg
// cap couldn't hold 192 pinned Q + working set -> one Q set was silently
// demoted to per-interval reloads (FETCH doubled). 2 waves/SIMD x 512 regs
// fits the 2048-reg pool, so occupancy (1 block/CU) is unchanged.
__global__ void __launch_bounds__(NTHR, 1) lstm_pipe(
    const u16* __restrict__ xh,
    const float* __restrict__ bias0, const float* __restrict__ bias1,
    const u16* __restrict__ Wxt0,
    const u16* __restrict__ Qt0, const u16* __restrict__ Qt01, const u16* __restrict__ Qt1,
    const u16* __restrict__ Pt1,
    u16* __restrict__ hb0, u16* __restrict__ hb1,   // [256][32][2048] f16 each (no-reuse)
    float* out, unsigned* arr) {
    __shared__ float part[8][64][20];
    __shared__ float zb0[32][33];
    __shared__ float zb1[32][33];
    __shared__ u16 hst0[32][8];
    __shared__ u16 hst1[32][8];

    const int tid = threadIdx.x, bid = blockIdx.x;
    const int wid = tid >> 6, lane = tid & 63;
    const int n = lane & 31, kg = lane >> 5;

    const int colmap = (n >> 3) * 2048 + bid * 8 + (n & 7);
    const size_t wx640 = (size_t)colmap * 640 + wid * 80 + kg * 8;    // Wxt0 slice
    const size_t qOff  = (size_t)colmap * 2048 + wid * 256 + kg * 8;  // Qt slices
    const size_t aXh   = (size_t)n * (256 * 640) + wid * 80 + kg * 8; // xh row n (f16), +t*640
    const size_t hROff = (size_t)n * 2048 + wid * 256 + kg * 8;       // h frag base

    // D layout: col=lane&31, row=(reg&3)+8*(reg>>2)+4*(lane>>5)
    const int rn = tid >> 4, rm0 = (tid & 15) * 2;
    const int ch = tid >> 5, cb = tid & 31;   // cell mapping (tid<256)

    const bool isT = bid < 40;
    const int  tb  = (bid < 20) ? bid : bid - 20;
    const int  par = (bid < 20) ? 0 : 1;
    const size_t pOff = (size_t)(tb * 32 + n) * 2048 + wid * 256 + kg * 8;

    const float bv0 = bias0[(rn >> 3) * 2048 + bid * 8 + (rn & 7)];
    const float bv1 = bias1[(rn >> 3) * 2048 + bid * 8 + (rn & 7)];

    // ---- load + PIN all three Q fragment sets (192 regs; fits the 512 cap) ----
    uint4 q0r[16], q01r[16], q1r[16];
    #pragma unroll
    for (int ks = 0; ks < 16; ++ks) {
        q0r[ks]  = *(const uint4*)(Qt0  + qOff + ks * 16);
        q01r[ks] = *(const uint4*)(Qt01 + qOff + ks * 16);
        q1r[ks]  = *(const uint4*)(Qt1  + qOff + ks * 16);
    }
    #pragma unroll
    for (int ks = 0; ks < 16; ++ks) {
        asm volatile("" : "+v"(q0r[ks].x),  "+v"(q0r[ks].y),  "+v"(q0r[ks].z),  "+v"(q0r[ks].w));
        asm volatile("" : "+v"(q01r[ks].x), "+v"(q01r[ks].y), "+v"(q01r[ks].z), "+v"(q01r[ks].w));
        asm volatile("" : "+v"(q1r[ks].x),  "+v"(q1r[ks].y),  "+v"(q1r[ks].z),  "+v"(q1r[ks].w));
    }

    float creg0 = 0.f, creg1 = 0.f;

    auto xp0 = [&](int t) -> f32x16 {   // xh(t) @ Wxt0, f16, 5 MFMAs (post-arrive)
        f32x16 a;
        #pragma unroll
        for (int r = 0; r < 16; ++r) a[r] = 0.f;
        const u16* xb = xh + aXh + (size_t)t * 640;
        const u16* wb = Wxt0 + wx640;
        #pragma unroll
        for (int ks = 0; ks < 5; ++ks)
            a = __builtin_amdgcn_mfma_f32_32x32x16_f16(*(const f16x8*)(xb + ks * 16),
                                                       *(const f16x8*)(wb + ks * 16), a, 0, 0, 0);
        return a;
    };
    auto stash = [&](const f32x16& v) {
        #pragma unroll
        for (int r = 0; r < 4; ++r) {
            float4 w;
            w.x = v[4 * r + 0]; w.y = v[4 * r + 1];
            w.z = v[4 * r + 2]; w.w = v[4 * r + 3];
            *(float4*)&part[wid][lane][4 * r] = w;
        }
    };
    auto sum8 = [&](int m) -> float {
        int lp = rn + 32 * ((m >> 2) & 1);
        int rg = (m & 3) + 4 * (m >> 3);
        float s = 0.f;
        #pragma unroll
        for (int w = 0; w < 8; ++w) s += part[w][lp][rg];
        return s;
    };

    f32x16 zacc0 = xp0(0);

    for (int g = 0; g <= 257; ++g) {
        if (g > 0) pollall(arr, (unsigned)g);   // h0(g-1), h1(g-2) + flags visible
        const int s = g - 1;                    // L1 step this interval
        const bool doL0 = (g <= 255);
        const bool doL1 = (s >= 0 && s <= 255);

        // ===== both gate chains: same h0(g-1) operand, independent accumulators =====
        f32x16 acc0, acc1;
        if (doL0) acc0 = zacc0;
        if (doL1) {
            #pragma unroll
            for (int r = 0; r < 16; ++r) acc1[r] = 0.f;
        }
        if (g >= 1) {
            const u16* h0c = hb0 + (size_t)(g - 1) * HSZ2 + hROff;
            if (doL0 && doL1) {
                #pragma unroll
                for (int ks = 0; ks < 16; ++ks) {
                    f16x8 a = *(const f16x8*)(h0c + ks * 16);
                    acc0 = __builtin_amdgcn_mfma_f32_32x32x16_f16(a, __builtin_bit_cast(f16x8, q0r[ks]),  acc0, 0, 0, 0);
                    acc1 = __builtin_amdgcn_mfma_f32_32x32x16_f16(a, __builtin_bit_cast(f16x8, q01r[ks]), acc1, 0, 0, 0);
                }
            } else if (doL0) {
                #pragma unroll
                for (int ks = 0; ks < 16; ++ks)
                    acc0 = __builtin_amdgcn_mfma_f32_32x32x16_f16(*(const f16x8*)(h0c + ks * 16),
                                                                  __builtin_bit_cast(f16x8, q0r[ks]), acc0, 0, 0, 0);
            } else if (doL1) {
                #pragma unroll
                for (int ks = 0; ks < 16; ++ks)
                    acc1 = __builtin_amdgcn_mfma_f32_32x32x16_f16(*(const f16x8*)(h0c + ks * 16),
                                                                  __builtin_bit_cast(f16x8, q01r[ks]), acc1, 0, 0, 0);
            }
        }
        if (s >= 1) {   // + h1(s-1) · Q1
            const u16* h1c = hb1 + (size_t)(s - 1) * HSZ2 + hROff;
            #pragma unroll
            for (int ks = 0; ks < 16; ++ks)
                acc1 = __builtin_amdgcn_mfma_f32_32x32x16_f16(*(const f16x8*)(h1c + ks * 16),
                                                              __builtin_bit_cast(f16x8, q1r[ks]), acc1, 0, 0, 0);
        }

        // ===== reduces (part shared, 2 passes) + cells =====
        if (doL0) {
            stash(acc0);
            __syncthreads();
            #pragma unroll
            for (int j = 0; j < 2; ++j) { int m = rm0 + j; zb0[rn][m] = sum8(m) + bv0; }
        }
        __syncthreads();
        if (doL1) {
            stash(acc1);
            __syncthreads();
            #pragma unroll
            for (int j = 0; j < 2; ++j) { int m = rm0 + j; zb1[rn][m] = sum8(m) + bv1; }
        }
        if (doL0 && tid < 256) {   // cell0 (gate order i, j, f, o) — zb0 stable 2 syncs ago
            float zi = zb0[0 * 8 + ch][cb];
            float zj = zb0[1 * 8 + ch][cb];
            float zf = zb0[2 * 8 + ch][cb];
            float zo = zb0[3 * 8 + ch][cb];
            float cn = sigm(zf + 1.0f) * creg0 + sigm(zi) * tanhf(zj);
            creg0 = cn;
            hst0[cb][ch] = __builtin_bit_cast(u16, (_Float16)(sigm(zo) * tanhf(cn)));
        }
        __syncthreads();
        if (doL1 && tid < 256) {   // cell1
            float zi = zb1[0 * 8 + ch][cb];
            float zj = zb1[1 * 8 + ch][cb];
            float zf = zb1[2 * 8 + ch][cb];
            float zo = zb1[3 * 8 + ch][cb];
            float cn = sigm(zf + 1.0f) * creg1 + sigm(zi) * tanhf(zj);
            creg1 = cn;
            hst1[cb][ch] = __builtin_bit_cast(u16, (_Float16)(sigm(zo) * tanhf(cn)));
        }
        __syncthreads();

        // ===== publish + arrive =====
        if (doL0 && wid == 0) {
            int b = tid >> 1, hf = tid & 1;
            u64 v = *(const u64*)&hst0[b][hf * 4];
            ast64(hb0 + (size_t)g * HSZ2 + (size_t)b * 2048 + bid * 8 + hf * 4, v);
        }
        if (doL1 && wid == 1) {
            int l = tid - 64;
            int b = l >> 1, hf = l & 1;
            u64 v = *(const u64*)&hst1[b][hf * 4];
            ast64(hb1 + (size_t)s * HSZ2 + (size_t)b * 2048 + bid * 8 + hf * 4, v);
        }
        __syncthreads();   // drains publish stores (vmcnt before s_barrier)
        if (tid == 0)
            __hip_atomic_store(arr + bid, (unsigned)(g + 1), __ATOMIC_RELAXED, __HIP_MEMORY_SCOPE_AGENT);

        // ===== post-arrive (off critical path) =====
        const int sp = g - 2;   // output step for teams; h1(sp) visible since poll(g)
        if (isT && sp >= 0 && (sp & 1) == par) {
            f32x16 pacc;
            #pragma unroll
            for (int r = 0; r < 16; ++r) pacc[r] = 0.f;
            const u16* hc = hb1 + (size_t)sp * HSZ2 + hROff;
            const u16* pf = Pt1 + pOff;
            #pragma unroll
            for (int ks = 0; ks < 16; ++ks)
                pacc = __builtin_amdgcn_mfma_f32_32x32x16_f16(*(const f16x8*)(hc + ks * 16),
                                                              *(const f16x8*)(pf + ks * 16), pacc, 0, 0, 0);
            __syncthreads();
            stash(pacc);
            __syncthreads();
            #pragma unroll
            for (int j = 0; j < 2; ++j) {
                int m = rm0 + j;
                out[((size_t)m * 256 + sp) * 640 + tb * 32 + rn] = sum8(m);
            }
        }
        if (g < 255) zacc0 = xp0(g + 1);
    }
}

// ---------- fallback (R1-style) if ws too small ----------
__device__ __forceinline__ void grid_bar_slow(unsigned int* bar, unsigned int& epoch) {
    __syncthreads();
    epoch++;
    if (threadIdx.x == 0) {
        __threadfence();
        atomicAdd(bar, 1u);
        const unsigned int target = epoch * NBLK;
        while (__hip_atomic_load(bar, __ATOMIC_RELAXED, __HIP_MEMORY_SCOPE_AGENT) < target)
            __builtin_amdgcn_s_sleep(1);
        __threadfence();
    }
    __syncthreads();
}

__global__ void __launch_bounds__(NTHR, 1) lstm_fb(
    const float* __restrict__ x,
    const float* __restrict__ W0, const float* __restrict__ b0, const float* __restrict__ Pr0,
    const float* __restrict__ W1, const float* __restrict__ b1, const float* __restrict__ Pr1,
    float* out, float* ws) {
    const int tid = threadIdx.x;
    const int bid = blockIdx.x;
    unsigned int* bar = (unsigned int*)ws;
    float* mbuf0 = ws + 1024;
    float* mbuf1 = mbuf0 + 32 * 640;
    float* hws = mbuf1 + 32 * 640;
    __shared__ float zbuf[32 * 33];
    __shared__ float pred[512];
    unsigned int epoch = 0;
    const int c_idx = tid & 31;
    const int bg = tid >> 5;
    const int b0r = bg * 2;
    const int col = (c_idx >> 3) * 2048 + bid * 8 + (c_idx & 7);
    const int ch = tid >> 5;
    const int cb = tid & 31;
    const int p_s = (bid * 640) / NBLK;
    const int p_e = ((bid + 1) * 640) / NBLK;
    const int np = p_e - p_s;
    const int kq_n = (np == 2) ? 8 : 4;
    const int klen = 2048 / kq_n;
    const int pg = tid >> 5;
    const bool pact = pg < np * kq_n;
    const int pj = pact ? (pg % np) : 0;
    const int kq = pact ? (pg / np) : 0;
    for (int layer = 0; layer < 2; ++layer) {
        const float* W = layer ? W1 : W0;
        const float* bbv = layer ? b1 : b0;
        const float* Pr = layer ? Pr1 : Pr0;
        const float* inb = layer ? (const float*)out : x;
        for (int i = bid * NTHR + tid; i < 32 * 640; i += NBLK * NTHR) mbuf0[i] = 0.0f;
        float creg = 0.0f;
        grid_bar_slow(bar, epoch);
        const float bias = bbv[col];
        for (int t = 0; t < 256; ++t) {
            float* mcur = (t & 1) ? mbuf1 : mbuf0;
            float* mnxt = (t & 1) ? mbuf0 : mbuf1;
            const float* in0 = inb + (size_t)(b0r * 256 + t) * 640;
            const float* in1 = in0 + (size_t)256 * 640;
            const float* wp = W + col;
            float a0 = 0.f, a1 = 0.f;
            #pragma unroll 4
            for (int k = 0; k < 640; k += 4) {
                float4 u0 = *(const float4*)(in0 + k);
                float4 u1 = *(const float4*)(in1 + k);
                float w0 = wp[(size_t)(k + 0) * 8192], w1 = wp[(size_t)(k + 1) * 8192];
                float w2 = wp[(size_t)(k + 2) * 8192], w3 = wp[(size_t)(k + 3) * 8192];
                a0 += w0 * u0.x + w1 * u0.y + w2 * u0.z + w3 * u0.w;
                a1 += w0 * u1.x + w1 * u1.y + w2 * u1.z + w3 * u1.w;
            }
            const float* q0 = mcur + (size_t)b0r * 640;
            const float* q1 = q0 + 640;
            #pragma unroll 4
            for (int k = 0; k < 640; k += 4) {
                float4 u0 = *(const float4*)(q0 + k);
                float4 u1 = *(const float4*)(q1 + k);
                float w0 = wp[(size_t)(640 + k + 0) * 8192], w1 = wp[(size_t)(640 + k + 1) * 8192];
                float w2 = wp[(size_t)(640 + k + 2) * 8192], w3 = wp[(size_t)(640 + k + 3) * 8192];
                a0 += w0 * u0.x + w1 * u0.y + w2 * u0.z + w3 * u0.w;
                a1 += w0 * u1.x + w1 * u1.y + w2 * u1.z + w3 * u1.w;
            }
            zbuf[c_idx * 33 + b0r + 0] = a0 + bias;
            zbuf[c_idx * 33 + b0r + 1] = a1 + bias;
            __syncthreads();
            if (tid < 256) {
                float zi = zbuf[(0 * 8 + ch) * 33 + cb];
                float zj = zbuf[(1 * 8 + ch) * 33 + cb];
                float zf = zbuf[(2 * 8 + ch) * 33 + cb];
                float zo = zbuf[(3 * 8 + ch) * 33 + cb];
                float cn = sigm(zf + 1.0f) * creg + sigm(zi) * tanhf(zj);
                creg = cn;
                hws[(size_t)(bid * 8 + ch) * 32 + cb] = sigm(zo) * tanhf(cn);
            }
            grid_bar_slow(bar, epoch);
            if (pact) {
                const int p = p_s + pj;
                const float* pp = Pr + p;
                const int k0 = kq * klen;
                float s = 0.f;
                #pragma unroll 4
                for (int k = k0; k < k0 + klen; ++k) s += hws[(size_t)k * 32 + cb] * pp[(size_t)k * 640];
                pred[(pj * 32 + cb) * kq_n + kq] = s;
            }
            __syncthreads();
            if (tid < np * 32) {
                float s = 0.f;
                for (int q2 = 0; q2 < kq_n; ++q2) s += pred[tid * kq_n + q2];
                const int p = p_s + (tid >> 5);
                const int b = tid & 31;
                mnxt[(size_t)b * 640 + p] = s;
                out[((size_t)b * 256 + t) * 640 + p] = s;
            }
            grid_bar_slow(bar, epoch);
        }
    }
}

extern "C" void kernel_launch(void* const* d_in, const int* in_sizes, int n_in,
                              void* d_out, int out_size, void* d_ws, size_t ws_size,
                              hipStream_t stream) {
    const float* x   = (const float*)d_in[0];
    const float* W0  = (const float*)d_in[1];
    const float* b0  = (const float*)d_in[2];
    const float* P0  = (const float*)d_in[3];
    const float* W1  = (const float*)d_in[4];
    const float* b1  = (const float*)d_in[5];
    const float* P1  = (const float*)d_in[6];
    float* out = (float*)d_out;

    // ws layout (bytes, 256-aligned). One transpose-plane pair reused serially.
    size_t off = 0;
    auto alloc = [&](size_t bytes) { size_t o = off; off += (bytes + 255) & ~(size_t)255; return o; };
    const size_t oBar  = alloc(32768);
    const size_t szW   = (size_t)8192 * 1280 * 2;  // bf16 plane (scratch, reused)
    const size_t szQ   = (size_t)8192 * 2048 * 2;  // Qt f16
    const size_t szPt  = (size_t)640 * 2048 * 2;   // Pt f16
    const size_t szWx  = (size_t)8192 * 640 * 2;   // Wxt f16
    const size_t oWH   = alloc(szW), oWL = alloc(szW);
    const size_t oQt0  = alloc(szQ), oQt01 = alloc(szQ), oQt1 = alloc(szQ);
    const size_t oPt1  = alloc(szPt);
    const size_t oWx0  = alloc(szWx);
    const size_t oXh   = alloc((size_t)32 * 256 * 640 * 2);
    const size_t oH0   = alloc((size_t)256 * HSZ2 * 2);   // no-reuse h rings
    const size_t oH1   = alloc((size_t)256 * HSZ2 * 2);
    const size_t need  = off;

    hipMemsetAsync(d_ws, 0, 32768, stream);  // barrier flags start at 0 every call

    if (ws_size < need) {  // fallback path (~0.5 MB ws)
        float* ws = (float*)d_ws;
        void* args[] = {(void*)&x, (void*)&W0, (void*)&b0, (void*)&P0,
                        (void*)&W1, (void*)&b1, (void*)&P1, (void*)&out, (void*)&ws};
        hipError_t err = hipLaunchCooperativeKernel((const void*)lstm_fb,
                                                    dim3(NBLK), dim3(NTHR), args, 0, stream);
        if (err != hipSuccess)
            lstm_fb<<<dim3(NBLK), dim3(NTHR), 0, stream>>>(x, W0, b0, P0, W1, b1, P1, out, ws);
        return;
    }

    char* w = (char*)d_ws;
    u16 *WHp = (u16*)(w + oWH), *WLp = (u16*)(w + oWL);
    u16 *Qt0p = (u16*)(w + oQt0), *Qt01p = (u16*)(w + oQt01), *Qt1p = (u16*)(w + oQt1);
    u16 *Pt1p = (u16*)(w + oPt1);
    u16 *Wx0p = (u16*)(w + oWx0);
    u16 *xhp  = (u16*)(w + oXh);
    u16 *hb0p = (u16*)(w + oH0), *hb1p = (u16*)(w + oH1);
    unsigned* arrp = (unsigned*)(w + oBar);

    // precompute (stream-ordered; plane pair reused between layers)
    transpose_split<<<dim3(256, 40), 256, 0, stream>>>(W0, WHp, WLp, 1280, 8192);
    qgemm<<<dim3(4096), 256, 0, stream>>>(P0, WHp, WLp, Qt0p, 640);   // Q0  = P0 @ Wm0
    transpose_split<<<dim3(256, 40), 256, 0, stream>>>(W1, WHp, WLp, 1280, 8192);
    qgemm<<<dim3(4096), 256, 0, stream>>>(P0, WHp, WLp, Qt01p, 0);    // Q01 = P0 @ Wx1
    qgemm<<<dim3(4096), 256, 0, stream>>>(P1, WHp, WLp, Qt1p, 640);   // Q1  = P1 @ Wm1
    transpose_f16<<<dim3(20, 64), 256, 0, stream>>>(P1, Pt1p, 2048, 640);
    transpose_f16<<<dim3(256, 20), 256, 0, stream>>>(W0, Wx0p, 640, 8192);
    xcast<<<dim3(5120), 256, 0, stream>>>(x, xhp, 32 * 256 * 640 / 4);

    const float *b0c = b0, *b1c = b1;
    void* args[] = {(void*)&xhp, (void*)&b0c, (void*)&b1c,
                    (void*)&Wx0p,
                    (void*)&Qt0p, (void*)&Qt01p, (void*)&Qt1p, (void*)&Pt1p,
                    (void*)&hb0p, (void*)&hb1p,
                    (void*)&out, (void*)&arrp};
    hipError_t err = hipLaunchCooperativeKernel((const void*)lstm_pipe,
                                                dim3(NBLK), dim3(NTHR), args, 0, stream);
    if (err != hipSuccess)
        lstm_pipe<<<dim3(NBLK), dim3(NTHR), 0, stream>>>(
            xhp, b0c, b1c, Wx0p, Qt0p, Qt01p, Qt1p, Pt1p, hb0p, hb1p, out, arrp);
}

// Round 13
// 5246.144 us; speedup vs baseline: 1.2968x; 1.1972x over previous
//
#include <hip/hip_runtime.h>
#include <math.h>

typedef __attribute__((ext_vector_type(8))) short s16x8;
typedef __attribute__((ext_vector_type(8))) _Float16 f16x8;
typedef __attribute__((ext_vector_type(16))) float f32x16;
typedef unsigned long long u64;
typedef unsigned short u16;

#define NBLK 256
#define NTHR 512

constexpr int HSZ2 = 32 * 2048;  // one h slot, f16 elems

__device__ __forceinline__ float sigm(float v) { return 1.0f / (1.0f + expf(-v)); }

__device__ __forceinline__ unsigned short bf16_rne(float x) {
    unsigned u = __float_as_uint(x);
    return (unsigned short)((u + 0x7FFFu + ((u >> 16) & 1u)) >> 16);
}
__device__ __forceinline__ void split2(float x, unsigned short& hi, unsigned short& lo) {
    unsigned u = __float_as_uint(x);
    hi = (unsigned short)(u >> 16);
    float hf = __uint_as_float(u & 0xFFFF0000u);
    lo = bf16_rne(x - hf);
}
__device__ __forceinline__ void split8(const float* f, s16x8& h, s16x8& l) {
    #pragma unroll
    for (int i = 0; i < 8; ++i) {
        unsigned short hh, ll;
        split2(f[i], hh, ll);
        h[i] = (short)hh; l[i] = (short)ll;
    }
}

// ---- agent-scope stores (publish path; readers use plain cached loads on no-reuse slots) ----
__device__ __forceinline__ void ast64(u16* p, u64 v) {
    __hip_atomic_store((u64*)p, v, __ATOMIC_RELAXED, __HIP_MEMORY_SCOPE_AGENT);
}

// ---- all-poll barrier ----
__device__ __forceinline__ void pollall(const unsigned* arr, unsigned e) {
    if (threadIdx.x < 64) {
        const int i0 = (int)threadIdx.x * 4;
        for (;;) {
            bool ok = (__hip_atomic_load(arr + i0 + 0, __ATOMIC_RELAXED, __HIP_MEMORY_SCOPE_AGENT) >= e) &&
                      (__hip_atomic_load(arr + i0 + 1, __ATOMIC_RELAXED, __HIP_MEMORY_SCOPE_AGENT) >= e) &&
                      (__hip_atomic_load(arr + i0 + 2, __ATOMIC_RELAXED, __HIP_MEMORY_SCOPE_AGENT) >= e) &&
                      (__hip_atomic_load(arr + i0 + 3, __ATOMIC_RELAXED, __HIP_MEMORY_SCOPE_AGENT) >= e);
            if (__all(ok)) break;
            __builtin_amdgcn_s_sleep(1);
        }
    }
    __syncthreads();
}

// ---------- precompute: transpose [R][C] fp32 -> [C][R] bf16 hi/lo ----------
__global__ void transpose_split(const float* __restrict__ in,
                                u16* __restrict__ outHi, u16* __restrict__ outLo,
                                int R, int C) {
    __shared__ float tile[32][33];
    const int c0 = blockIdx.x * 32, r0 = blockIdx.y * 32;
    const int tid = threadIdx.x;  // 256
    {
        int r = tid >> 3, q = (tid & 7) * 4;
        float4 v = *(const float4*)(in + (size_t)(r0 + r) * C + c0 + q);
        tile[q + 0][r] = v.x; tile[q + 1][r] = v.y;
        tile[q + 2][r] = v.z; tile[q + 3][r] = v.w;
    }
    __syncthreads();
    {
        int c = tid >> 3, q = (tid & 7) * 4;
        ushort4 h, l;
        unsigned short hh, ll;
        split2(tile[c][q + 0], hh, ll); h.x = hh; l.x = ll;
        split2(tile[c][q + 1], hh, ll); h.y = hh; l.y = ll;
        split2(tile[c][q + 2], hh, ll); h.z = hh; l.z = ll;
        split2(tile[c][q + 3], hh, ll); h.w = hh; l.w = ll;
        size_t o = (size_t)(c0 + c) * R + r0 + q;
        *(ushort4*)(outHi + o) = h;
        *(ushort4*)(outLo + o) = l;
    }
}

// ---------- precompute: transpose [R][C] fp32 -> [C][R] f16 ----------
__global__ void transpose_f16(const float* __restrict__ in, u16* __restrict__ outp,
                              int R, int C) {
    __shared__ float tile[32][33];
    const int c0 = blockIdx.x * 32, r0 = blockIdx.y * 32;
    const int tid = threadIdx.x;  // 256
    {
        int r = tid >> 3, q = (tid & 7) * 4;
        float4 v = *(const float4*)(in + (size_t)(r0 + r) * C + c0 + q);
        tile[q + 0][r] = v.x; tile[q + 1][r] = v.y;
        tile[q + 2][r] = v.z; tile[q + 3][r] = v.w;
    }
    __syncthreads();
    {
        int c = tid >> 3, q = (tid & 7) * 4;
        ushort4 o;
        o.x = __builtin_bit_cast(u16, (_Float16)tile[c][q + 0]);
        o.y = __builtin_bit_cast(u16, (_Float16)tile[c][q + 1]);
        o.z = __builtin_bit_cast(u16, (_Float16)tile[c][q + 2]);
        o.w = __builtin_bit_cast(u16, (_Float16)tile[c][q + 3]);
        *(ushort4*)(outp + (size_t)(c0 + c) * R + r0 + q) = o;
    }
}

// ---------- precompute: x f32 -> f16 (same layout) ----------
__global__ void xcast(const float* __restrict__ in, u16* __restrict__ outp, int n4) {
    int i = blockIdx.x * blockDim.x + threadIdx.x;
    if (i < n4) {
        float4 v = ((const float4*)in)[i];
        ushort4 o;
        o.x = __builtin_bit_cast(u16, (_Float16)v.x);
        o.y = __builtin_bit_cast(u16, (_Float16)v.y);
        o.z = __builtin_bit_cast(u16, (_Float16)v.z);
        o.w = __builtin_bit_cast(u16, (_Float16)v.w);
        ((ushort4*)outp)[i] = o;
    }
}

// ---------- precompute: Qt[8192][2048] f16 = (P[2048][640] @ Wpart[640][8192])^T ----------
// rowOff selects the W k-rows: 0 = x/m0-input part, 640 = recurrent part.
__global__ void __launch_bounds__(256) qgemm(const float* __restrict__ P,
    const u16* __restrict__ WH, const u16* __restrict__ WL,
    u16* __restrict__ Qt, int rowOff) {
    const int tid = threadIdx.x;
    const int wid = tid >> 6, lane = tid & 63;
    const int n = lane & 31, kg = lane >> 5;
    const int tile = blockIdx.x * 4 + wid;
    const int ct = tile & 255, kt = tile >> 8;
    const int col = ct * 32 + n;
    const int krow = kt * 32 + n;

    f32x16 acc;
    #pragma unroll
    for (int r = 0; r < 16; ++r) acc[r] = 0.f;

    const float* ap = P + (size_t)krow * 640 + kg * 8;
    const u16* bhp = WH + (size_t)col * 1280 + rowOff + kg * 8;
    const u16* blp = WL + (size_t)col * 1280 + rowOff + kg * 8;
    #pragma unroll 4
    for (int ks = 0; ks < 40; ++ks) {
        float4 v0 = *(const float4*)(ap + ks * 16);
        float4 v1 = *(const float4*)(ap + ks * 16 + 4);
        float f[8] = {v0.x, v0.y, v0.z, v0.w, v1.x, v1.y, v1.z, v1.w};
        s16x8 ah, al;
        split8(f, ah, al);
        s16x8 bh = *(const s16x8*)(bhp + ks * 16);
        s16x8 bl = *(const s16x8*)(blp + ks * 16);
        acc = __builtin_amdgcn_mfma_f32_32x32x16_bf16(ah, bh, acc, 0, 0, 0);
        acc = __builtin_amdgcn_mfma_f32_32x32x16_bf16(ah, bl, acc, 0, 0, 0);
        acc = __builtin_amdgcn_mfma_f32_32x32x16_bf16(al, bh, acc, 0, 0, 0);
    }
    u16* qrow = Qt + (size_t)col * 2048 + kt * 32 + 4 * kg;
    #pragma unroll
    for (int q = 0; q < 4; ++q) {
        ushort4 o;
        o.x = __builtin_bit_cast(u16, (_Float16)acc[4 * q + 0]);
        o.y = __builtin_bit_cast(u16, (_Float16)acc[4 * q + 1]);
        o.z = __builtin_bit_cast(u16, (_Float16)acc[4 * q + 2]);
        o.w = __builtin_bit_cast(u16, (_Float16)acc[4 * q + 3]);
        *(ushort4*)(qrow + 8 * q) = o;
    }
}

// ---------- main persistent kernel ----------
// Recurrence loop (257 uniform intervals, 3 syncs each, NO projection):
//   z0(g) = x(g)Wx0 + h0(g-1)Q0        (Q0  = P0@Wm0)
//   z1(s) = h0(s)Q01 + h1(s-1)Q1, s=g-1 (Q01 = P0@Wx1, Q1 = P1@Wm1)
//   cell0 on threads 0-255, cell1 on threads 256-511 (concurrent).
// Then one barrier-free batch GEMM: out = h1_ring · P1 (R12 lesson: team-block
// post-arrive projection made 40 stragglers per interval; now all blocks uniform).
__global__ void __launch_bounds__(NTHR, 1) lstm_pipe(
    const u16* __restrict__ xh,
    const float* __restrict__ bias0, const float* __restrict__ bias1,
    const u16* __restrict__ Wxt0,
    const u16* __restrict__ Qt0, const u16* __restrict__ Qt01, const u16* __restrict__ Qt1,
    const u16* __restrict__ Pt1,
    u16* __restrict__ hb0, u16* __restrict__ hb1,   // [256][32][2048] f16 each (no-reuse)
    float* out, unsigned* arr) {
    __shared__ float part0[8][64][20];   // L0 gate partials
    __shared__ float part1[8][64][20];   // L1 gate partials
    __shared__ u16 hst0[32][8];
    __shared__ u16 hst1[32][8];

    const int tid = threadIdx.x, bid = blockIdx.x;
    const int wid = tid >> 6, lane = tid & 63;
    const int n = lane & 31, kg = lane >> 5;

    const int colmap = (n >> 3) * 2048 + bid * 8 + (n & 7);
    const size_t wx640 = (size_t)colmap * 640 + wid * 80 + kg * 8;    // Wxt0 slice
    const size_t qOff  = (size_t)colmap * 2048 + wid * 256 + kg * 8;  // Qt slices
    const size_t aXh   = (size_t)n * (256 * 640) + wid * 80 + kg * 8; // xh row n (f16), +t*640
    const size_t hROff = (size_t)n * 2048 + wid * 256 + kg * 8;       // h frag base

    // D layout: col=lane&31 (B-lane), row=(reg&3)+8*(reg>>2)+4*(lane>>5) (A-lane)
    const int rn = tid >> 4, rm0 = (tid & 15) * 2;   // final-GEMM reduce mapping

    // cell roles: threads 0-255 -> layer0 cell, 256-511 -> layer1 cell
    const bool isC0 = tid < 256;
    const int cl = tid & 255;
    const int ch = cl >> 5, cb = cl & 31;
    float bv[4];
    #pragma unroll
    for (int gx = 0; gx < 4; ++gx)
        bv[gx] = (isC0 ? bias0 : bias1)[gx * 2048 + bid * 8 + ch];
    const int crg = (cb & 3) + 4 * (cb >> 3);        // D reg for row cb
    const int clp = 32 * ((cb >> 2) & 1);            // D lane-offset for row cb

    // ---- load + PIN all three Q fragment sets ----
    uint4 q0r[16], q01r[16], q1r[16];
    #pragma unroll
    for (int ks = 0; ks < 16; ++ks) {
        q0r[ks]  = *(const uint4*)(Qt0  + qOff + ks * 16);
        q01r[ks] = *(const uint4*)(Qt01 + qOff + ks * 16);
        q1r[ks]  = *(const uint4*)(Qt1  + qOff + ks * 16);
    }
    #pragma unroll
    for (int ks = 0; ks < 16; ++ks) {
        asm volatile("" : "+v"(q0r[ks].x),  "+v"(q0r[ks].y),  "+v"(q0r[ks].z),  "+v"(q0r[ks].w));
        asm volatile("" : "+v"(q01r[ks].x), "+v"(q01r[ks].y), "+v"(q01r[ks].z), "+v"(q01r[ks].w));
        asm volatile("" : "+v"(q1r[ks].x),  "+v"(q1r[ks].y),  "+v"(q1r[ks].z),  "+v"(q1r[ks].w));
    }

    float creg = 0.f;   // c-state: layer0 cell in threads 0-255, layer1 cell in 256-511

    auto xp0 = [&](int t) -> f32x16 {   // xh(t) @ Wxt0, f16, 5 MFMAs (post-flag prefetch)
        f32x16 a;
        #pragma unroll
        for (int r = 0; r < 16; ++r) a[r] = 0.f;
        const u16* xb = xh + aXh + (size_t)t * 640;
        const u16* wb = Wxt0 + wx640;
        #pragma unroll
        for (int ks = 0; ks < 5; ++ks)
            a = __builtin_amdgcn_mfma_f32_32x32x16_f16(*(const f16x8*)(xb + ks * 16),
                                                       *(const f16x8*)(wb + ks * 16), a, 0, 0, 0);
        return a;
    };
    auto stash = [&](float (*prt)[64][20], const f32x16& v) {
        #pragma unroll
        for (int r = 0; r < 4; ++r) {
            float4 w;
            w.x = v[4 * r + 0]; w.y = v[4 * r + 1];
            w.z = v[4 * r + 2]; w.w = v[4 * r + 3];
            *(float4*)&prt[wid][lane][4 * r] = w;
        }
    };

    f32x16 zacc0 = xp0(0);

    for (int g = 0; g <= 256; ++g) {
        if (g > 0) pollall(arr, (unsigned)g);   // h0(g-1), h1(g-2) visible
        const int s = g - 1;                    // L1 step this interval
        const bool doL0 = (g <= 255);
        const bool doL1 = (s >= 0);

        // ===== gate MFMAs: h0(g-1) shared by both layers =====
        f32x16 acc0, acc1;
        if (doL0) acc0 = zacc0;
        if (doL1) {
            #pragma unroll
            for (int r = 0; r < 16; ++r) acc1[r] = 0.f;
        }
        if (g >= 1) {
            const u16* h0c = hb0 + (size_t)(g - 1) * HSZ2 + hROff;
            if (doL0) {
                #pragma unroll
                for (int ks = 0; ks < 16; ++ks) {
                    f16x8 a = *(const f16x8*)(h0c + ks * 16);
                    acc0 = __builtin_amdgcn_mfma_f32_32x32x16_f16(a, __builtin_bit_cast(f16x8, q0r[ks]),  acc0, 0, 0, 0);
                    acc1 = __builtin_amdgcn_mfma_f32_32x32x16_f16(a, __builtin_bit_cast(f16x8, q01r[ks]), acc1, 0, 0, 0);
                }
            } else {
                #pragma unroll
                for (int ks = 0; ks < 16; ++ks)
                    acc1 = __builtin_amdgcn_mfma_f32_32x32x16_f16(*(const f16x8*)(h0c + ks * 16),
                                                                  __builtin_bit_cast(f16x8, q01r[ks]), acc1, 0, 0, 0);
            }
        }
        if (s >= 1) {   // + h1(s-1) · Q1
            const u16* h1c = hb1 + (size_t)(s - 1) * HSZ2 + hROff;
            #pragma unroll
            for (int ks = 0; ks < 16; ++ks)
                acc1 = __builtin_amdgcn_mfma_f32_32x32x16_f16(*(const f16x8*)(h1c + ks * 16),
                                                              __builtin_bit_cast(f16x8, q1r[ks]), acc1, 0, 0, 0);
        }

        // ===== stash -> cells (direct 8-way sums, both layers concurrent) =====
        if (doL0) stash(part0, acc0);
        if (doL1) stash(part1, acc1);
        __syncthreads();   // (A)
        if ((isC0 && doL0) || (!isC0 && doL1)) {
            float (*prt)[64][20] = isC0 ? part0 : part1;
            float z[4];
            #pragma unroll
            for (int gx = 0; gx < 4; ++gx) {
                const int lp = (gx * 8 + ch) + clp;
                float ssum = 0.f;
                #pragma unroll
                for (int w = 0; w < 8; ++w) ssum += prt[w][lp][crg];
                z[gx] = ssum + bv[gx];
            }
            float cn = sigm(z[2] + 1.0f) * creg + sigm(z[0]) * tanhf(z[1]);
            creg = cn;
            u16 hv = __builtin_bit_cast(u16, (_Float16)(sigm(z[3]) * tanhf(cn)));
            if (isC0) hst0[cb][ch] = hv;
            else      hst1[cb][ch] = hv;
        }
        __syncthreads();   // (B)

        // ===== publish + arrive =====
        if (doL0 && wid == 0) {
            int b = tid >> 1, hf = tid & 1;
            u64 v = *(const u64*)&hst0[b][hf * 4];
            ast64(hb0 + (size_t)g * HSZ2 + (size_t)b * 2048 + bid * 8 + hf * 4, v);
        }
        if (doL1 && wid == 1) {
            int l = tid - 64;
            int b = l >> 1, hf = l & 1;
            u64 v = *(const u64*)&hst1[b][hf * 4];
            ast64(hb1 + (size_t)s * HSZ2 + (size_t)b * 2048 + bid * 8 + hf * 4, v);
        }
        __syncthreads();   // (C) drains publish stores (vmcnt before s_barrier)
        if (tid == 0)
            __hip_atomic_store(arr + bid, (unsigned)(g + 1), __ATOMIC_RELAXED, __HIP_MEMORY_SCOPE_AGENT);

        if (g < 255) zacc0 = xp0(g + 1);   // prefetch next x-part (off critical path)
    }

    // ===== final batch GEMM: out[r][p] = h1_ring · P1, r = b*256+t =====
    pollall(arr, 257u);   // all h1 slots published
    const int mb = bid >> 3;              // batch of this row-tile
    const int t0 = (bid * 32) & 255;      // first timestep of this row-tile
    const size_t aOff = (size_t)(t0 + n) * HSZ2 + (size_t)mb * 2048 + wid * 256 + kg * 8;
    for (int ct = 0; ct < 20; ++ct) {
        f32x16 pacc;
        #pragma unroll
        for (int r = 0; r < 16; ++r) pacc[r] = 0.f;
        const u16* ap = hb1 + aOff;
        const u16* bp = Pt1 + (size_t)(ct * 32 + n) * 2048 + wid * 256 + kg * 8;
        #pragma unroll
        for (int ks = 0; ks < 16; ++ks)
            pacc = __builtin_amdgcn_mfma_f32_32x32x16_f16(*(const f16x8*)(ap + ks * 16),
                                                          *(const f16x8*)(bp + ks * 16), pacc, 0, 0, 0);
        __syncthreads();
        stash(part0, pacc);
        __syncthreads();
        #pragma unroll
        for (int j = 0; j < 2; ++j) {
            int m = rm0 + j;
            int lp = rn + 32 * ((m >> 2) & 1);
            int rg = (m & 3) + 4 * (m >> 3);
            float ssum = 0.f;
            #pragma unroll
            for (int w = 0; w < 8; ++w) ssum += part0[w][lp][rg];
            out[(size_t)(bid * 32 + m) * 640 + ct * 32 + rn] = ssum;
        }
    }
}

// ---------- fallback (R1-style) if ws too small ----------
__device__ __forceinline__ void grid_bar_slow(unsigned int* bar, unsigned int& epoch) {
    __syncthreads();
    epoch++;
    if (threadIdx.x == 0) {
        __threadfence();
        atomicAdd(bar, 1u);
        const unsigned int target = epoch * NBLK;
        while (__hip_atomic_load(bar, __ATOMIC_RELAXED, __HIP_MEMORY_SCOPE_AGENT) < target)
            __builtin_amdgcn_s_sleep(1);
        __threadfence();
    }
    __syncthreads();
}

__global__ void __launch_bounds__(NTHR, 1) lstm_fb(
    const float* __restrict__ x,
    const float* __restrict__ W0, const float* __restrict__ b0, const float* __restrict__ Pr0,
    const float* __restrict__ W1, const float* __restrict__ b1, const float* __restrict__ Pr1,
    float* out, float* ws) {
    const int tid = threadIdx.x;
    const int bid = blockIdx.x;
    unsigned int* bar = (unsigned int*)ws;
    float* mbuf0 = ws + 1024;
    float* mbuf1 = mbuf0 + 32 * 640;
    float* hws = mbuf1 + 32 * 640;
    __shared__ float zbuf[32 * 33];
    __shared__ float pred[512];
    unsigned int epoch = 0;
    const int c_idx = tid & 31;
    const int bg = tid >> 5;
    const int b0r = bg * 2;
    const int col = (c_idx >> 3) * 2048 + bid * 8 + (c_idx & 7);
    const int ch = tid >> 5;
    const int cb = tid & 31;
    const int p_s = (bid * 640) / NBLK;
    const int p_e = ((bid + 1) * 640) / NBLK;
    const int np = p_e - p_s;
    const int kq_n = (np == 2) ? 8 : 4;
    const int klen = 2048 / kq_n;
    const int pg = tid >> 5;
    const bool pact = pg < np * kq_n;
    const int pj = pact ? (pg % np) : 0;
    const int kq = pact ? (pg / np) : 0;
    for (int layer = 0; layer < 2; ++layer) {
        const float* W = layer ? W1 : W0;
        const float* bbv = layer ? b1 : b0;
        const float* Pr = layer ? Pr1 : Pr0;
        const float* inb = layer ? (const float*)out : x;
        for (int i = bid * NTHR + tid; i < 32 * 640; i += NBLK * NTHR) mbuf0[i] = 0.0f;
        float creg = 0.0f;
        grid_bar_slow(bar, epoch);
        const float bias = bbv[col];
        for (int t = 0; t < 256; ++t) {
            float* mcur = (t & 1) ? mbuf1 : mbuf0;
            float* mnxt = (t & 1) ? mbuf0 : mbuf1;
            const float* in0 = inb + (size_t)(b0r * 256 + t) * 640;
            const float* in1 = in0 + (size_t)256 * 640;
            const float* wp = W + col;
            float a0 = 0.f, a1 = 0.f;
            #pragma unroll 4
            for (int k = 0; k < 640; k += 4) {
                float4 u0 = *(const float4*)(in0 + k);
                float4 u1 = *(const float4*)(in1 + k);
                float w0 = wp[(size_t)(k + 0) * 8192], w1 = wp[(size_t)(k + 1) * 8192];
                float w2 = wp[(size_t)(k + 2) * 8192], w3 = wp[(size_t)(k + 3) * 8192];
                a0 += w0 * u0.x + w1 * u0.y + w2 * u0.z + w3 * u0.w;
                a1 += w0 * u1.x + w1 * u1.y + w2 * u1.z + w3 * u1.w;
            }
            const float* q0 = mcur + (size_t)b0r * 640;
            const float* q1 = q0 + 640;
            #pragma unroll 4
            for (int k = 0; k < 640; k += 4) {
                float4 u0 = *(const float4*)(q0 + k);
                float4 u1 = *(const float4*)(q1 + k);
                float w0 = wp[(size_t)(640 + k + 0) * 8192], w1 = wp[(size_t)(640 + k + 1) * 8192];
                float w2 = wp[(size_t)(640 + k + 2) * 8192], w3 = wp[(size_t)(640 + k + 3) * 8192];
                a0 += w0 * u0.x + w1 * u0.y + w2 * u0.z + w3 * u0.w;
                a1 += w0 * u1.x + w1 * u1.y + w2 * u1.z + w3 * u1.w;
            }
            zbuf[c_idx * 33 + b0r + 0] = a0 + bias;
            zbuf[c_idx * 33 + b0r + 1] = a1 + bias;
            __syncthreads();
            if (tid < 256) {
                float zi = zbuf[(0 * 8 + ch) * 33 + cb];
                float zj = zbuf[(1 * 8 + ch) * 33 + cb];
                float zf = zbuf[(2 * 8 + ch) * 33 + cb];
                float zo = zbuf[(3 * 8 + ch) * 33 + cb];
                float cn = sigm(zf + 1.0f) * creg + sigm(zi) * tanhf(zj);
                creg = cn;
                hws[(size_t)(bid * 8 + ch) * 32 + cb] = sigm(zo) * tanhf(cn);
            }
            grid_bar_slow(bar, epoch);
            if (pact) {
                const int p = p_s + pj;
                const float* pp = Pr + p;
                const int k0 = kq * klen;
                float s = 0.f;
                #pragma unroll 4
                for (int k = k0; k < k0 + klen; ++k) s += hws[(size_t)k * 32 + cb] * pp[(size_t)k * 640];
                pred[(pj * 32 + cb) * kq_n + kq] = s;
            }
            __syncthreads();
            if (tid < np * 32) {
                float s = 0.f;
                for (int q2 = 0; q2 < kq_n; ++q2) s += pred[tid * kq_n + q2];
                const int p = p_s + (tid >> 5);
                const int b = tid & 31;
                mnxt[(size_t)b * 640 + p] = s;
                out[((size_t)b * 256 + t) * 640 + p] = s;
            }
            grid_bar_slow(bar, epoch);
        }
    }
}

extern "C" void kernel_launch(void* const* d_in, const int* in_sizes, int n_in,
                              void* d_out, int out_size, void* d_ws, size_t ws_size,
                              hipStream_t stream) {
    const float* x   = (const float*)d_in[0];
    const float* W0  = (const float*)d_in[1];
    const float* b0  = (const float*)d_in[2];
    const float* P0  = (const float*)d_in[3];
    const float* W1  = (const float*)d_in[4];
    const float* b1  = (const float*)d_in[5];
    const float* P1  = (const float*)d_in[6];
    float* out = (float*)d_out;

    // ws layout (bytes, 256-aligned). One transpose-plane pair reused serially.
    size_t off = 0;
    auto alloc = [&](size_t bytes) { size_t o = off; off += (bytes + 255) & ~(size_t)255; return o; };
    const size_t oBar  = alloc(32768);
    const size_t szW   = (size_t)8192 * 1280 * 2;  // bf16 plane (scratch, reused)
    const size_t szQ   = (size_t)8192 * 2048 * 2;  // Qt f16
    const size_t szPt  = (size_t)640 * 2048 * 2;   // Pt f16
    const size_t szWx  = (size_t)8192 * 640 * 2;   // Wxt f16
    const size_t oWH   = alloc(szW), oWL = alloc(szW);
    const size_t oQt0  = alloc(szQ), oQt01 = alloc(szQ), oQt1 = alloc(szQ);
    const size_t oPt1  = alloc(szPt);
    const size_t oWx0  = alloc(szWx);
    const size_t oXh   = alloc((size_t)32 * 256 * 640 * 2);
    const size_t oH0   = alloc((size_t)256 * HSZ2 * 2);   // no-reuse h rings
    const size_t oH1   = alloc((size_t)256 * HSZ2 * 2);
    const size_t need  = off;

    hipMemsetAsync(d_ws, 0, 32768, stream);  // barrier flags start at 0 every call

    if (ws_size < need) {  // fallback path (~0.5 MB ws)
        float* ws = (float*)d_ws;
        void* args[] = {(void*)&x, (void*)&W0, (void*)&b0, (void*)&P0,
                        (void*)&W1, (void*)&b1, (void*)&P1, (void*)&out, (void*)&ws};
        hipError_t err = hipLaunchCooperativeKernel((const void*)lstm_fb,
                                                    dim3(NBLK), dim3(NTHR), args, 0, stream);
        if (err != hipSuccess)
            lstm_fb<<<dim3(NBLK), dim3(NTHR), 0, stream>>>(x, W0, b0, P0, W1, b1, P1, out, ws);
        return;
    }

    char* w = (char*)d_ws;
    u16 *WHp = (u16*)(w + oWH), *WLp = (u16*)(w + oWL);
    u16 *Qt0p = (u16*)(w + oQt0), *Qt01p = (u16*)(w + oQt01), *Qt1p = (u16*)(w + oQt1);
    u16 *Pt1p = (u16*)(w + oPt1);
    u16 *Wx0p = (u16*)(w + oWx0);
    u16 *xhp  = (u16*)(w + oXh);
    u16 *hb0p = (u16*)(w + oH0), *hb1p = (u16*)(w + oH1);
    unsigned* arrp = (unsigned*)(w + oBar);

    // precompute (stream-ordered; plane pair reused between layers)
    transpose_split<<<dim3(256, 40), 256, 0, stream>>>(W0, WHp, WLp, 1280, 8192);
    qgemm<<<dim3(4096), 256, 0, stream>>>(P0, WHp, WLp, Qt0p, 640);   // Q0  = P0 @ Wm0
    transpose_split<<<dim3(256, 40), 256, 0, stream>>>(W1, WHp, WLp, 1280, 8192);
    qgemm<<<dim3(4096), 256, 0, stream>>>(P0, WHp, WLp, Qt01p, 0);    // Q01 = P0 @ Wx1
    qgemm<<<dim3(4096), 256, 0, stream>>>(P1, WHp, WLp, Qt1p, 640);   // Q1  = P1 @ Wm1
    transpose_f16<<<dim3(20, 64), 256, 0, stream>>>(P1, Pt1p, 2048, 640);
    transpose_f16<<<dim3(256, 20), 256, 0, stream>>>(W0, Wx0p, 640, 8192);
    xcast<<<dim3(5120), 256, 0, stream>>>(x, xhp, 32 * 256 * 640 / 4);

    const float *b0c = b0, *b1c = b1;
    void* args[] = {(void*)&xhp, (void*)&b0c, (void*)&b1c,
                    (void*)&Wx0p,
                    (void*)&Qt0p, (void*)&Qt01p, (void*)&Qt1p, (void*)&Pt1p,
                    (void*)&hb0p, (void*)&hb1p,
                    (void*)&out, (void*)&arrp};
    hipError_t err = hipLaunchCooperativeKernel((const void*)lstm_pipe,
                                                dim3(NBLK), dim3(NTHR), args, 0, stream);
    if (err != hipSuccess)
        lstm_pipe<<<dim3(NBLK), dim3(NTHR), 0, stream>>>(
            xhp, b0c, b1c, Wx0p, Qt0p, Qt01p, Qt1p, Pt1p, hb0p, hb1p, out, arrp);
}